// Round 1
// 60.853 us; speedup vs baseline: 1.0164x; 1.0164x over previous
//
#include <hip/hip_runtime.h>
#include <math.h>

// QuantumKernel closed form (derivation in R0/R1 notes):
//   amplitude(s) = prod_w f_w(a_w(s)), f_w(0)=cos(t/2), f_w(1)=sin(t/2);
//   CNOT-ring inverse: a_0=s0^s21, a_1=s1^s0^s21, a_k=s_k^s_{k-1} (k=2..21).
//   out(b,i,j) = U1[(g>>9)&511] * U2[g&511] * absM[s0,s1,s19][i][j],
//   g = b^(b>>1)  (core bits c_k = g bit (19-k), k=2..19),
//   U1[i] = |prod_{q=0..8} (fx*fy)[2*(10-q)+bit_q(i)]|   (wires 2..10),
//   U2[i] = |prod_{p=0..8} (fx*fy)[2*(19-p)+bit_p(i)]|   (wires 11..19),
//   absM[m][i][j] = |sum_k Ycorner(i,k)*Xcorner(k,j)|    (wires 0,1,20,21).
//
// R-this: amortize the per-block prologue 4x. 256 blocks x 512 threads x QPT=8
// (1 block/CU): table fill is 1 entry/thread, h[] computed inline in the
// sincos stage (2 barriers instead of 3), total redundant table work drops
// from 1024*1024 to 256*1024 nine-term products. Hot loop unchanged:
// 3 LDS reads + ~10 VALU + 1 coalesced float4 store per output quad.
// Store-bound floor: 16.8 MB / 6.3 TB/s ~= 2.7 us.

#define BLOCKS 256
#define THREADS 512
#define QPT 8   // 256 * 512 * 8 = 2^20 float4 outputs

__global__ __launch_bounds__(THREADS) void qk_fused(
    const float* __restrict__ x, const float* __restrict__ y,
    float* __restrict__ out)
{
    __shared__ float fx[44], fy[44], h[44];
    __shared__ float U1[512], U2[512];
    __shared__ float absM[32];
    const int t = threadIdx.x;

    // Stage 1: one wave computes sincos for both inputs AND the elementwise
    // product h = fx*fy inline (saves the old separate h-stage + barrier).
    if (t < 22) {
        float sxv, cxv, syv, cyv;
        sincosf(0.5f * x[t], &sxv, &cxv);
        sincosf(0.5f * y[t], &syv, &cyv);
        fx[2 * t] = cxv; fx[2 * t + 1] = sxv;
        fy[2 * t] = cyv; fy[2 * t + 1] = syv;
        h[2 * t] = cxv * cyv; h[2 * t + 1] = sxv * syv;
    }
    __syncthreads();

    // Stage 2: table fill — exactly one U1/U2 entry per thread (512 threads).
    {
        const int i = t;
        float p1 = 1.0f, p2 = 1.0f;
#pragma unroll
        for (int q = 0; q < 9; ++q) {
            const int bit = (i >> q) & 1;
            p1 *= h[2 * (10 - q) + bit];
            p2 *= h[2 * (19 - q) + bit];
        }
        U1[i] = fabsf(p1);
        U2[i] = fabsf(p2);
    }
    if (t < 8) {
        const int s0 = (t >> 2) & 1, s1 = (t >> 1) & 1, s19 = t & 1;
#pragma unroll
        for (int ii = 0; ii < 2; ++ii) {
#pragma unroll
            for (int j = 0; j < 2; ++j) {
                float sum = 0.0f;
#pragma unroll
                for (int k = 0; k < 2; ++k) {
                    // X corner: s20=k, s21=j ; Y corner: s20=ii, s21=k
                    float kx = fx[s0 ^ j] * fx[2 + (s1 ^ s0 ^ j)]
                             * fx[40 + (k ^ s19)] * fx[42 + (j ^ k)];
                    float ky = fy[s0 ^ k] * fy[2 + (s1 ^ s0 ^ k)]
                             * fy[40 + (ii ^ s19)] * fy[42 + (k ^ ii)];
                    sum += ky * kx;
                }
                absM[4 * t + 2 * ii + j] = fabsf(sum);
            }
        }
    }
    __syncthreads();

    // Stage 3: hot loop. Per float4 output: U1 read is wave-broadcast,
    // U2 read is 64 consecutive dwords lane-permuted (2 lanes/bank = free),
    // absM is a 2-address ds_read_b128; store is a coalesced dwordx4.
    const unsigned base = blockIdx.x * (unsigned)(THREADS * QPT);
#pragma unroll
    for (int k = 0; k < QPT; ++k) {
        const unsigned b = base + k * (unsigned)THREADS + (unsigned)t;
        const unsigned g = b ^ (b >> 1);
        const float p = U1[(g >> 9) & 511u] * U2[g & 511u];
        const unsigned m = ((b >> 17) & 6u) | (b & 1u);    // s0<<2 | s1<<1 | s19
        const float4 a = reinterpret_cast<const float4*>(absM)[m];
        float4 o;
        o.x = p * a.x; o.y = p * a.y; o.z = p * a.z; o.w = p * a.w;
        reinterpret_cast<float4*>(out)[b] = o;
    }
}

extern "C" void kernel_launch(void* const* d_in, const int* in_sizes, int n_in,
                              void* d_out, int out_size, void* d_ws, size_t ws_size,
                              hipStream_t stream) {
    const float* x = (const float*)d_in[0];
    const float* y = (const float*)d_in[1];
    float* out = (float*)d_out;   // 2^22 floats
    qk_fused<<<BLOCKS, THREADS, 0, stream>>>(x, y, out);
}